// Round 2
// baseline (127.708 us; speedup 1.0000x reference)
//
#include <hip/hip_runtime.h>
#include <hip/hip_bf16.h>

// IG-MSA (transposed channel attention), restructured:
//   K1: XX[b] = x[b] @ x[b]^T   (64x64 Gram of channels over n=65536)
//   K2: G = Wk^T XX Wq per head; norms from quadratic forms; softmax;
//       fold with Wp -> M[b, i=256, c=64] (bf16)
//   K3: out[b,c,n] = M^T @ ((Wv^T x) * (WL^T illu)) + bp   (MFMA, bf16)

#define NPOS 65536
#define CH 64
#define INNER 256

typedef __attribute__((ext_vector_type(8))) __bf16 bfrag;
typedef __attribute__((ext_vector_type(4))) float facc;
typedef __attribute__((ext_vector_type(4))) float fvec4;

__device__ __forceinline__ unsigned short f2bu(float f) {
  return __builtin_bit_cast(unsigned short, (__bf16)f);
}

// ---------------- K1: channel Gram matrix ----------------
__global__ __launch_bounds__(256) void k1_xx(const float* __restrict__ x,
                                             float* __restrict__ xx) {
  const int b = blockIdx.y;
  const int wave = threadIdx.x >> 6, lane = threadIdx.x & 63;
  const int r = lane & 15, g = lane >> 4;
  const int gw = blockIdx.x * 4 + wave;   // 0..127 waves per b (gridDim.x == 32)
  const int per = NPOS / 128;             // 512 n per wave
  const size_t n0 = (size_t)gw * per;
  const float* xb = x + (size_t)b * CH * NPOS;

  facc acc[4][4] = {};

  for (int n = 0; n < per; n += 32) {
    bfrag fr[4];
#pragma unroll
    for (int t = 0; t < 4; ++t) {
      const float* p = xb + (size_t)(16 * t + r) * NPOS + n0 + n + g * 8;
      fvec4 lo = *(const fvec4*)p;
      fvec4 hi = *(const fvec4*)(p + 4);
      bfrag f;
#pragma unroll
      for (int e = 0; e < 4; ++e) { f[e] = (__bf16)lo[e]; f[e + 4] = (__bf16)hi[e]; }
      fr[t] = f;
    }
#pragma unroll
    for (int ti = 0; ti < 4; ++ti)
#pragma unroll
      for (int tj = 0; tj < 4; ++tj)
        acc[ti][tj] = __builtin_amdgcn_mfma_f32_16x16x32_bf16(fr[ti], fr[tj],
                                                              acc[ti][tj], 0, 0, 0);
  }

  __shared__ float red[4][4096];
  float* my = red[wave];
#pragma unroll
  for (int ti = 0; ti < 4; ++ti)
#pragma unroll
    for (int tj = 0; tj < 4; ++tj)
#pragma unroll
      for (int q = 0; q < 4; ++q)
        my[(16 * ti + g * 4 + q) * 64 + 16 * tj + r] = acc[ti][tj][q];
  __syncthreads();
  float* xxb = xx + (size_t)b * 4096;
  for (int i = threadIdx.x; i < 4096; i += 256)
    atomicAdd(xxb + i, red[0][i] + red[1][i] + red[2][i] + red[3][i]);
}

// ---------------- K2: finalize attention, fold Wp ----------------
__global__ __launch_bounds__(256) void k2_attn(
    const float* __restrict__ xx, const float* __restrict__ Wq,
    const float* __restrict__ Wk, const float* __restrict__ rescale,
    const float* __restrict__ Wp, unsigned short* __restrict__ Mt) {
  const int b = blockIdx.x >> 2, h = blockIdx.x & 3;
  const int t = threadIdx.x;
  __shared__ float sXX[64][64];   // XX, later G, later attn
  __shared__ float sWq[64][64];   // Wq[:, h*64+e]
  __shared__ float sWk[64][64];
  __shared__ float sT1q[64][64];  // XX @ Wq_h
  __shared__ float sT1k[64][64];  // XX @ Wk_h, later Wp_h
  __shared__ float sNq[64], sNk[64];

  const float* xxb = xx + (size_t)b * 4096;
  for (int idx = t; idx < 4096; idx += 256) {
    int c = idx >> 6, e = idx & 63;
    sXX[c][e] = xxb[idx];
    sWq[c][e] = Wq[c * INNER + h * 64 + e];
    sWk[c][e] = Wk[c * INNER + h * 64 + e];
  }
  __syncthreads();
  for (int idx = t; idx < 4096; idx += 256) {
    int c = idx >> 6, e = idx & 63;
    float aq = 0.f, ak = 0.f;
    for (int cc = 0; cc < 64; ++cc) {
      float xv = sXX[c][cc];
      aq += xv * sWq[cc][e];
      ak += xv * sWk[cc][e];
    }
    sT1q[c][e] = aq; sT1k[c][e] = ak;
  }
  __syncthreads();
  // G (reads sWk/sT1q only -> safe to overwrite sXX)
  for (int idx = t; idx < 4096; idx += 256) {
    int d = idx >> 6, e = idx & 63;
    float gs = 0.f;
    for (int c = 0; c < 64; ++c) gs += sWk[c][d] * sT1q[c][e];
    sXX[d][e] = gs;
  }
  if (t < 64) {
    float s = 0.f;
    for (int c = 0; c < 64; ++c) s += sWq[c][t] * sT1q[c][t];
    sNq[t] = s;
  } else if (t < 128) {
    int d = t - 64;
    float s = 0.f;
    for (int c = 0; c < 64; ++c) s += sWk[c][d] * sT1k[c][d];
    sNk[d] = s;
  }
  __syncthreads();
  // Wp_h into sT1k (T1k consumed)
  for (int idx = t; idx < 4096; idx += 256) {
    int d = idx >> 6, c2 = idx & 63;
    sT1k[d][c2] = Wp[(h * 64 + d) * CH + c2];
  }
  // softmax per row d over e (thread t<64 owns row t)
  if (t < 64) {
    const int d = t;
    const float rsc = rescale[h];
    const float invk = rsc / fmaxf(sqrtf(sNk[d]), 1e-12f);
    float mx = -1e30f;
    for (int e = 0; e < 64; ++e) {
      float le = sXX[d][e] * invk / fmaxf(sqrtf(sNq[e]), 1e-12f);
      mx = fmaxf(mx, le);
    }
    float sum = 0.f;
    for (int e = 0; e < 64; ++e) {
      float le = sXX[d][e] * invk / fmaxf(sqrtf(sNq[e]), 1e-12f);
      float ex = __expf(le - mx);
      sXX[d][e] = ex; sum += ex;
    }
    float inv = 1.f / sum;
    for (int e = 0; e < 64; ++e) sXX[d][e] *= inv;
  }
  __syncthreads();
  // M[i=h*64+e][c'] = sum_d attn[d][e] * Wp[h*64+d][c']; store transposed Mt[b][c'][i] bf16
  for (int idx = t; idx < 4096; idx += 256) {
    int e = idx >> 6, c2 = idx & 63;
    float m = 0.f;
    for (int d = 0; d < 64; ++d) m += sXX[d][e] * sT1k[d][c2];
    Mt[((size_t)(b * CH + c2)) * INNER + h * 64 + e] = f2bu(m);
  }
}

// ---------------- K3: gated V + folded output projection ----------------
__global__ __launch_bounds__(256) void k3_out(
    const float* __restrict__ x, const float* __restrict__ illu,
    const float* __restrict__ Wv, const float* __restrict__ WL,
    const unsigned short* __restrict__ Mt, const float* __restrict__ bp,
    float* __restrict__ out) {
  const int b = blockIdx.y;
  const int wave = threadIdx.x >> 6, lane = threadIdx.x & 63;
  const int r = lane & 15, g = lane >> 4;
  const int BJ = 512;                       // n per block (gridDim.x == 128)
  const int n0 = blockIdx.x * BJ;

  __shared__ char lxs[2][8192];   // x  tile [j][c] bf16, row 128B, XOR-swizzled
  __shared__ char lis[2][8192];   // illu tile
  __shared__ char lvs[2][8192];   // v tile [j 16][i 256] bf16, row 512B, swizzled

  // --- per-wave weight fragments (A-operands) ---
  bfrag wvA[4][2], wlA[4][2], mtA[8];
#pragma unroll
  for (int ti = 0; ti < 4; ++ti) {
#pragma unroll
    for (int s = 0; s < 2; ++s) {
      bfrag fv, fl;
      const int i = wave * 64 + ti * 16 + r;
#pragma unroll
      for (int e = 0; e < 8; ++e) {
        const int c = 32 * s + g * 8 + e;
        fv[e] = (__bf16)Wv[c * INNER + i];
        fl[e] = (__bf16)WL[c * INNER + i];
      }
      wvA[ti][s] = fv; wlA[ti][s] = fl;
    }
  }
#pragma unroll
  for (int s8 = 0; s8 < 8; ++s8)
    mtA[s8] = *(const bfrag*)(Mt + ((size_t)(b * CH + wave * 16 + r)) * INNER + s8 * 32 + g * 8);
  float bcol[4];
#pragma unroll
  for (int q = 0; q < 4; ++q) bcol[q] = bp[wave * 16 + g * 4 + q];

  const float* xb = x + (size_t)b * CH * NPOS;
  const float* ib = illu + (size_t)b * CH * NPOS;
  float* ob = out + (size_t)b * CH * NPOS;

  const int sc2 = threadIdx.x >> 3;        // 0..31 c-pair
  const int sjo = (threadIdx.x & 7) * 8;   // j offset within 64-chunk

  for (int chunk = 0; chunk < BJ / 64; ++chunk) {
    const int cb = chunk & 1;
    const int nbase = n0 + chunk * 64;
    // ---- stage x, illu (f32 -> bf16, transposed to [j][c], swizzled) ----
    {
      const float* px0 = xb + (size_t)(2 * sc2) * NPOS + nbase + sjo;
      const float* pi0 = ib + (size_t)(2 * sc2) * NPOS + nbase + sjo;
      fvec4 xa0 = *(const fvec4*)px0,         xa1 = *(const fvec4*)(px0 + 4);
      fvec4 xb0 = *(const fvec4*)(px0 + NPOS), xb1 = *(const fvec4*)(px0 + NPOS + 4);
      fvec4 ia0 = *(const fvec4*)pi0,         ia1 = *(const fvec4*)(pi0 + 4);
      fvec4 ib0 = *(const fvec4*)(pi0 + NPOS), ib1 = *(const fvec4*)(pi0 + NPOS + 4);
#pragma unroll
      for (int jj = 0; jj < 8; ++jj) {
        const int j = sjo + jj;
        const int byte = (sc2 * 4) ^ ((j & 7) << 4);
        float x0 = jj < 4 ? xa0[jj & 3] : xa1[jj & 3];
        float x1 = jj < 4 ? xb0[jj & 3] : xb1[jj & 3];
        float i0 = jj < 4 ? ia0[jj & 3] : ia1[jj & 3];
        float i1 = jj < 4 ? ib0[jj & 3] : ib1[jj & 3];
        *(unsigned int*)(lxs[cb] + j * 128 + byte) =
            (unsigned int)f2bu(x0) | ((unsigned int)f2bu(x1) << 16);
        *(unsigned int*)(lis[cb] + j * 128 + byte) =
            (unsigned int)f2bu(i0) | ((unsigned int)f2bu(i1) << 16);
      }
    }
    __syncthreads();

#pragma unroll
    for (int sub = 0; sub < 4; ++sub) {
      const int vb = sub & 1;
      const int j0 = sub * 16;
      const int j = j0 + r;
      // B-fragments of x / illu from LDS
      bfrag xB[2], iB[2];
#pragma unroll
      for (int s = 0; s < 2; ++s) {
        const int byte = (s * 64 + g * 16) ^ ((j & 7) << 4);
        xB[s] = *(const bfrag*)(lxs[cb] + j * 128 + byte);
        iB[s] = *(const bfrag*)(lis[cb] + j * 128 + byte);
      }
      facc av[4] = {}, gv[4] = {};
#pragma unroll
      for (int ti = 0; ti < 4; ++ti) {
#pragma unroll
        for (int s = 0; s < 2; ++s) {
          av[ti] = __builtin_amdgcn_mfma_f32_16x16x32_bf16(wvA[ti][s], xB[s], av[ti], 0, 0, 0);
          gv[ti] = __builtin_amdgcn_mfma_f32_16x16x32_bf16(wlA[ti][s], iB[s], gv[ti], 0, 0, 0);
        }
      }
      // gate + write v tile (C-layout rows i = wave*64+ti*16+g*4+q, col j = r)
#pragma unroll
      for (int ti = 0; ti < 4; ++ti) {
        const float v0 = av[ti][0] * gv[ti][0], v1 = av[ti][1] * gv[ti][1];
        const float v2 = av[ti][2] * gv[ti][2], v3 = av[ti][3] * gv[ti][3];
        const int i = wave * 64 + ti * 16 + g * 4;
        const int sw = (r & 7) << 4;
        *(unsigned int*)(lvs[vb] + r * 512 + ((i * 2) ^ sw)) =
            (unsigned int)f2bu(v0) | ((unsigned int)f2bu(v1) << 16);
        *(unsigned int*)(lvs[vb] + r * 512 + (((i + 2) * 2) ^ sw)) =
            (unsigned int)f2bu(v2) | ((unsigned int)f2bu(v3) << 16);
      }
      __syncthreads();
      // out tile: M^T @ v  (K = i = 256)
      facc ov = {0.f, 0.f, 0.f, 0.f};
#pragma unroll
      for (int s8 = 0; s8 < 8; ++s8) {
        const int byte = (s8 * 64 + g * 16) ^ ((r & 7) << 4);
        bfrag vB = *(const bfrag*)(lvs[vb] + r * 512 + byte);
        ov = __builtin_amdgcn_mfma_f32_16x16x32_bf16(mtA[s8], vB, ov, 0, 0, 0);
      }
#pragma unroll
      for (int q = 0; q < 4; ++q)
        ob[(size_t)(wave * 16 + g * 4 + q) * NPOS + nbase + j0 + r] = ov[q] + bcol[q];
      __syncthreads();
    }
  }
}

extern "C" void kernel_launch(void* const* d_in, const int* in_sizes, int n_in,
                              void* d_out, int out_size, void* d_ws, size_t ws_size,
                              hipStream_t stream) {
  (void)in_sizes; (void)n_in; (void)out_size; (void)ws_size;
  const float* x    = (const float*)d_in[0];
  const float* illu = (const float*)d_in[1];
  const float* Wq   = (const float*)d_in[2];
  const float* Wk   = (const float*)d_in[3];
  const float* Wv   = (const float*)d_in[4];
  const float* WL   = (const float*)d_in[5];
  const float* rsc  = (const float*)d_in[6];
  const float* Wp   = (const float*)d_in[7];
  const float* bp   = (const float*)d_in[8];
  float* out = (float*)d_out;

  float* xxws = (float*)d_ws;                                    // 4*4096 f32
  unsigned short* Mt = (unsigned short*)((char*)d_ws + 4 * 4096 * sizeof(float));

  hipMemsetAsync(d_ws, 0, (size_t)4 * 4096 * sizeof(float), stream);
  hipLaunchKernelGGL(k1_xx, dim3(32, 4), dim3(256), 0, stream, x, xxws);
  hipLaunchKernelGGL(k2_attn, dim3(16), dim3(256), 0, stream, xxws, Wq, Wk, rsc, Wp, Mt);
  hipLaunchKernelGGL(k3_out, dim3(128, 4), dim3(256), 0, stream, x, illu, Wv, WL, Mt, bp, out);
}

// Round 4
// 82.453 us; speedup vs baseline: 1.5489x; 1.5489x over previous
//
#include <hip/hip_runtime.h>
#include <hip/hip_bf16.h>

// IG-MSA (transposed channel attention), restructured:
//   K1: XX[b] = x[b] @ x[b]^T   (64x64 Gram of channels over n=65536)
//   K2: (MFMA) Zq=Wq^T XX, Zk=Wk^T XX; G=Zk Wq; norms=diag(Zq Wq / Zk Wk);
//       softmax; M = attn^T Wp  -> Mt[b, c', i] bf16
//   K3: out[b,c,n] = M^T @ ((Wv^T x) * (WL^T illu)) + bp   (MFMA, bf16)

#define NPOS 65536
#define CH 64
#define INNER 256

typedef __attribute__((ext_vector_type(8))) __bf16 bfrag;
typedef __attribute__((ext_vector_type(4))) float facc;
typedef __attribute__((ext_vector_type(4))) float fvec4;

__device__ __forceinline__ unsigned short f2bu(float f) {
  return __builtin_bit_cast(unsigned short, (__bf16)f);
}

// swizzled byte address inside a 64x64 bf16 tile (row stride 128B)
#define SWA(row, colbyte) ((row) * 128 + ((colbyte) ^ (((row) & 7) << 4)))

// ---------------- K1: channel Gram matrix ----------------
__global__ __launch_bounds__(256) void k1_xx(const float* __restrict__ x,
                                             float* __restrict__ xx) {
  const int b = blockIdx.y;
  const int wave = threadIdx.x >> 6, lane = threadIdx.x & 63;
  const int r = lane & 15, g = lane >> 4;
  const int gw = blockIdx.x * 4 + wave;   // 0..127 waves per b (gridDim.x == 32)
  const int per = NPOS / 128;             // 512 n per wave
  const size_t n0 = (size_t)gw * per;
  const float* xb = x + (size_t)b * CH * NPOS;

  facc acc[4][4] = {};

  for (int n = 0; n < per; n += 32) {
    bfrag fr[4];
#pragma unroll
    for (int t = 0; t < 4; ++t) {
      const float* p = xb + (size_t)(16 * t + r) * NPOS + n0 + n + g * 8;
      fvec4 lo = *(const fvec4*)p;
      fvec4 hi = *(const fvec4*)(p + 4);
      bfrag f;
#pragma unroll
      for (int e = 0; e < 4; ++e) { f[e] = (__bf16)lo[e]; f[e + 4] = (__bf16)hi[e]; }
      fr[t] = f;
    }
#pragma unroll
    for (int ti = 0; ti < 4; ++ti)
#pragma unroll
      for (int tj = 0; tj < 4; ++tj)
        acc[ti][tj] = __builtin_amdgcn_mfma_f32_16x16x32_bf16(fr[ti], fr[tj],
                                                              acc[ti][tj], 0, 0, 0);
  }

  __shared__ float red[4][4096];
  float* my = red[wave];
#pragma unroll
  for (int ti = 0; ti < 4; ++ti)
#pragma unroll
    for (int tj = 0; tj < 4; ++tj)
#pragma unroll
      for (int q = 0; q < 4; ++q)
        my[(16 * ti + g * 4 + q) * 64 + 16 * tj + r] = acc[ti][tj][q];
  __syncthreads();
  float* xxb = xx + (size_t)b * 4096;
  for (int i = threadIdx.x; i < 4096; i += 256)
    atomicAdd(xxb + i, red[0][i] + red[1][i] + red[2][i] + red[3][i]);
}

// ---------------- K2: MFMA finalize attention, fold Wp ----------------
__global__ __launch_bounds__(256) void k2_attn(
    const float* __restrict__ xx, const float* __restrict__ Wq,
    const float* __restrict__ Wk, const float* __restrict__ rescale,
    const float* __restrict__ Wp, unsigned short* __restrict__ Mt) {
  const int b = blockIdx.x >> 2, h = blockIdx.x & 3;
  const int t = threadIdx.x;
  const int wave = t >> 6, lane = t & 63;
  const int r = lane & 15, g = lane >> 4;

  __shared__ __align__(16) char tXX[8192];  // XX rows, bf16, swizzled
  __shared__ __align__(16) char tWq[8192];  // Wq^T rows: tWq[e][c]
  __shared__ __align__(16) char tWk[8192];  // Wk^T rows
  __shared__ __align__(16) char tWp[8192];  // Wp^T rows: tWp[c'][d]
  __shared__ __align__(16) char tZq[8192];  // Zq rows
  __shared__ __align__(16) char tZk[8192];  // Zk rows
  __shared__ __align__(16) char tAt[8192];  // attn^T rows: tAt[e][d]
  __shared__ float gG[64][68];
  __shared__ float sMx[64][4], sSm[64][4];
  __shared__ float sNq[64], sNk[64];

  // ---- load XX (f32->bf16) and transposed weight slices ----
  const float* xxb = xx + (size_t)b * 4096;
#pragma unroll
  for (int rep = 0; rep < 16; ++rep) {
    int idx = rep * 256 + t;
    int row = idx >> 6, col = idx & 63;
    *(unsigned short*)(tXX + SWA(row, col * 2)) = f2bu(xxb[idx]);
    // Wq/Wk: element (c=row, e=col) -> tW*[e][c]
    float vq = Wq[row * INNER + h * 64 + col];
    float vk = Wk[row * INNER + h * 64 + col];
    *(unsigned short*)(tWq + SWA(col, row * 2)) = f2bu(vq);
    *(unsigned short*)(tWk + SWA(col, row * 2)) = f2bu(vk);
    // Wp: element (d=row, c2=col) -> tWp[c2][d]
    *(unsigned short*)(tWp + SWA(col, row * 2)) = f2bu(Wp[(h * 64 + row) * CH + col]);
  }
  __syncthreads();

  // ---- stage 2: Zq = Wq^T XX, Zk = Wk^T XX (uses XX symmetry for B) ----
  facc zq[4] = {}, zk[4] = {};
#pragma unroll
  for (int s = 0; s < 2; ++s) {
    bfrag aq = *(const bfrag*)(tWq + SWA(16 * wave + r, s * 64 + g * 16));
    bfrag ak = *(const bfrag*)(tWk + SWA(16 * wave + r, s * 64 + g * 16));
#pragma unroll
    for (int tj = 0; tj < 4; ++tj) {
      bfrag bx = *(const bfrag*)(tXX + SWA(16 * tj + r, s * 64 + g * 16));
      zq[tj] = __builtin_amdgcn_mfma_f32_16x16x32_bf16(aq, bx, zq[tj], 0, 0, 0);
      zk[tj] = __builtin_amdgcn_mfma_f32_16x16x32_bf16(ak, bx, zk[tj], 0, 0, 0);
    }
  }
#pragma unroll
  for (int tj = 0; tj < 4; ++tj)
#pragma unroll
    for (int q = 0; q < 4; ++q) {
      int row = 16 * wave + g * 4 + q, colb = (16 * tj + r) * 2;
      *(unsigned short*)(tZq + SWA(row, colb)) = f2bu(zq[tj][q]);
      *(unsigned short*)(tZk + SWA(row, colb)) = f2bu(zk[tj][q]);
    }
  __syncthreads();

  // ---- stage 4: G = Zk*Wq ; Q2 = Zq*Wq ; K2m = Zk*Wk (diag only used) ----
  facc ga[4] = {}, q2[4] = {}, k2[4] = {};
#pragma unroll
  for (int s = 0; s < 2; ++s) {
    bfrag azk = *(const bfrag*)(tZk + SWA(16 * wave + r, s * 64 + g * 16));
    bfrag azq = *(const bfrag*)(tZq + SWA(16 * wave + r, s * 64 + g * 16));
#pragma unroll
    for (int tj = 0; tj < 4; ++tj) {
      bfrag bq = *(const bfrag*)(tWq + SWA(16 * tj + r, s * 64 + g * 16));
      bfrag bk = *(const bfrag*)(tWk + SWA(16 * tj + r, s * 64 + g * 16));
      ga[tj] = __builtin_amdgcn_mfma_f32_16x16x32_bf16(azk, bq, ga[tj], 0, 0, 0);
      q2[tj] = __builtin_amdgcn_mfma_f32_16x16x32_bf16(azq, bq, q2[tj], 0, 0, 0);
      k2[tj] = __builtin_amdgcn_mfma_f32_16x16x32_bf16(azk, bk, k2[tj], 0, 0, 0);
    }
  }
#pragma unroll
  for (int tj = 0; tj < 4; ++tj)
#pragma unroll
    for (int q = 0; q < 4; ++q) {
      int row = 16 * wave + g * 4 + q, col = 16 * tj + r;
      gG[row][col] = ga[tj][q];
      if (row == col) { sNq[row] = q2[tj][q]; sNk[row] = k2[tj][q]; }
    }
  __syncthreads();

  if (t < 64) {
    sNq[t] = 1.f / fmaxf(sqrtf(sNq[t]), 1e-12f);
    sNk[t] = rescale[h] / fmaxf(sqrtf(sNk[t]), 1e-12f);
  }
  __syncthreads();

  // ---- softmax over e per row d (4 threads per row) ----
  {
    const int d = t >> 2, p = t & 3;
    const float ik = sNk[d];
    float le[16];
    float mx = -1e30f;
#pragma unroll
    for (int j = 0; j < 16; ++j) {
      float v = gG[d][16 * p + j] * ik * sNq[16 * p + j];
      le[j] = v; mx = fmaxf(mx, v);
    }
    sMx[d][p] = mx;
    __syncthreads();
    mx = fmaxf(fmaxf(sMx[d][0], sMx[d][1]), fmaxf(sMx[d][2], sMx[d][3]));
    float sm = 0.f;
#pragma unroll
    for (int j = 0; j < 16; ++j) { le[j] = __expf(le[j] - mx); sm += le[j]; }
    sSm[d][p] = sm;
    __syncthreads();
    sm = sSm[d][0] + sSm[d][1] + sSm[d][2] + sSm[d][3];
    const float inv = 1.f / sm;
#pragma unroll
    for (int j = 0; j < 16; ++j) {
      int e = 16 * p + j;
      *(unsigned short*)(tAt + SWA(e, d * 2)) = f2bu(le[j] * inv);
    }
  }
  __syncthreads();

  // ---- stage 6: M = attn^T * Wp ; write Mt[b][c'][h*64+e] bf16 ----
  facc m[4] = {};
#pragma unroll
  for (int s = 0; s < 2; ++s) {
    bfrag aa = *(const bfrag*)(tAt + SWA(16 * wave + r, s * 64 + g * 16));
#pragma unroll
    for (int tj = 0; tj < 4; ++tj) {
      bfrag bw = *(const bfrag*)(tWp + SWA(16 * tj + r, s * 64 + g * 16));
      m[tj] = __builtin_amdgcn_mfma_f32_16x16x32_bf16(aa, bw, m[tj], 0, 0, 0);
    }
  }
#pragma unroll
  for (int tj = 0; tj < 4; ++tj)
#pragma unroll
    for (int q = 0; q < 4; ++q) {
      int e = 16 * wave + g * 4 + q, c2 = 16 * tj + r;
      Mt[((size_t)(b * CH + c2)) * INNER + h * 64 + e] = f2bu(m[tj][q]);
    }
}

// ---------------- K3: gated V + folded output projection ----------------
__global__ __launch_bounds__(256) void k3_out(
    const float* __restrict__ x, const float* __restrict__ illu,
    const float* __restrict__ Wv, const float* __restrict__ WL,
    const unsigned short* __restrict__ Mt, const float* __restrict__ bp,
    float* __restrict__ out) {
  const int b = blockIdx.y;
  const int wave = threadIdx.x >> 6, lane = threadIdx.x & 63;
  const int r = lane & 15, g = lane >> 4;
  const int BJ = 512;                       // n per block (gridDim.x == 128)
  const int n0 = blockIdx.x * BJ;

  __shared__ char lxs[2][8192];   // x  tile [j][c] bf16, row 128B, XOR-swizzled
  __shared__ char lis[2][8192];   // illu tile
  __shared__ char lvs[2][8192];   // v tile [j 16][i 256] bf16, row 512B, swizzled

  // --- per-wave weight fragments (A-operands) ---
  bfrag wvA[4][2], wlA[4][2], mtA[8];
#pragma unroll
  for (int ti = 0; ti < 4; ++ti) {
#pragma unroll
    for (int s = 0; s < 2; ++s) {
      bfrag fv, fl;
      const int i = wave * 64 + ti * 16 + r;
#pragma unroll
      for (int e = 0; e < 8; ++e) {
        const int c = 32 * s + g * 8 + e;
        fv[e] = (__bf16)Wv[c * INNER + i];
        fl[e] = (__bf16)WL[c * INNER + i];
      }
      wvA[ti][s] = fv; wlA[ti][s] = fl;
    }
  }
#pragma unroll
  for (int s8 = 0; s8 < 8; ++s8)
    mtA[s8] = *(const bfrag*)(Mt + ((size_t)(b * CH + wave * 16 + r)) * INNER + s8 * 32 + g * 8);
  float bcol[4];
#pragma unroll
  for (int q = 0; q < 4; ++q) bcol[q] = bp[wave * 16 + g * 4 + q];

  const float* xb = x + (size_t)b * CH * NPOS;
  const float* ib = illu + (size_t)b * CH * NPOS;
  float* ob = out + (size_t)b * CH * NPOS;

  const int sc2 = threadIdx.x >> 3;        // 0..31 c-pair
  const int sjo = (threadIdx.x & 7) * 8;   // j offset within 64-chunk

  for (int chunk = 0; chunk < BJ / 64; ++chunk) {
    const int cb = chunk & 1;
    const int nbase = n0 + chunk * 64;
    // ---- stage x, illu (f32 -> bf16, transposed to [j][c], swizzled) ----
    {
      const float* px0 = xb + (size_t)(2 * sc2) * NPOS + nbase + sjo;
      const float* pi0 = ib + (size_t)(2 * sc2) * NPOS + nbase + sjo;
      fvec4 xa0 = *(const fvec4*)px0,         xa1 = *(const fvec4*)(px0 + 4);
      fvec4 xb0 = *(const fvec4*)(px0 + NPOS), xb1 = *(const fvec4*)(px0 + NPOS + 4);
      fvec4 ia0 = *(const fvec4*)pi0,         ia1 = *(const fvec4*)(pi0 + 4);
      fvec4 ib0 = *(const fvec4*)(pi0 + NPOS), ib1 = *(const fvec4*)(pi0 + NPOS + 4);
#pragma unroll
      for (int jj = 0; jj < 8; ++jj) {
        const int j = sjo + jj;
        const int byte = (sc2 * 4) ^ ((j & 7) << 4);
        float x0 = jj < 4 ? xa0[jj & 3] : xa1[jj & 3];
        float x1 = jj < 4 ? xb0[jj & 3] : xb1[jj & 3];
        float i0 = jj < 4 ? ia0[jj & 3] : ia1[jj & 3];
        float i1 = jj < 4 ? ib0[jj & 3] : ib1[jj & 3];
        *(unsigned int*)(lxs[cb] + j * 128 + byte) =
            (unsigned int)f2bu(x0) | ((unsigned int)f2bu(x1) << 16);
        *(unsigned int*)(lis[cb] + j * 128 + byte) =
            (unsigned int)f2bu(i0) | ((unsigned int)f2bu(i1) << 16);
      }
    }
    __syncthreads();

#pragma unroll
    for (int sub = 0; sub < 4; ++sub) {
      const int vb = sub & 1;
      const int j0 = sub * 16;
      const int j = j0 + r;
      // B-fragments of x / illu from LDS
      bfrag xB[2], iB[2];
#pragma unroll
      for (int s = 0; s < 2; ++s) {
        const int byte = (s * 64 + g * 16) ^ ((j & 7) << 4);
        xB[s] = *(const bfrag*)(lxs[cb] + j * 128 + byte);
        iB[s] = *(const bfrag*)(lis[cb] + j * 128 + byte);
      }
      facc av[4] = {}, gv[4] = {};
#pragma unroll
      for (int ti = 0; ti < 4; ++ti) {
#pragma unroll
        for (int s = 0; s < 2; ++s) {
          av[ti] = __builtin_amdgcn_mfma_f32_16x16x32_bf16(wvA[ti][s], xB[s], av[ti], 0, 0, 0);
          gv[ti] = __builtin_amdgcn_mfma_f32_16x16x32_bf16(wlA[ti][s], iB[s], gv[ti], 0, 0, 0);
        }
      }
      // gate + write v tile (C-layout rows i = wave*64+ti*16+g*4+q, col j = r)
#pragma unroll
      for (int ti = 0; ti < 4; ++ti) {
        const float v0 = av[ti][0] * gv[ti][0], v1 = av[ti][1] * gv[ti][1];
        const float v2 = av[ti][2] * gv[ti][2], v3 = av[ti][3] * gv[ti][3];
        const int i = wave * 64 + ti * 16 + g * 4;
        const int sw = (r & 7) << 4;
        *(unsigned int*)(lvs[vb] + r * 512 + ((i * 2) ^ sw)) =
            (unsigned int)f2bu(v0) | ((unsigned int)f2bu(v1) << 16);
        *(unsigned int*)(lvs[vb] + r * 512 + (((i + 2) * 2) ^ sw)) =
            (unsigned int)f2bu(v2) | ((unsigned int)f2bu(v3) << 16);
      }
      __syncthreads();
      // out tile: M^T @ v  (K = i = 256)
      facc ov = {0.f, 0.f, 0.f, 0.f};
#pragma unroll
      for (int s8 = 0; s8 < 8; ++s8) {
        const int byte = (s8 * 64 + g * 16) ^ ((r & 7) << 4);
        bfrag vB = *(const bfrag*)(lvs[vb] + r * 512 + byte);
        ov = __builtin_amdgcn_mfma_f32_16x16x32_bf16(mtA[s8], vB, ov, 0, 0, 0);
      }
#pragma unroll
      for (int q = 0; q < 4; ++q)
        ob[(size_t)(wave * 16 + g * 4 + q) * NPOS + nbase + j0 + r] = ov[q] + bcol[q];
      __syncthreads();
    }
  }
}

extern "C" void kernel_launch(void* const* d_in, const int* in_sizes, int n_in,
                              void* d_out, int out_size, void* d_ws, size_t ws_size,
                              hipStream_t stream) {
  (void)in_sizes; (void)n_in; (void)out_size; (void)ws_size;
  const float* x    = (const float*)d_in[0];
  const float* illu = (const float*)d_in[1];
  const float* Wq   = (const float*)d_in[2];
  const float* Wk   = (const float*)d_in[3];
  const float* Wv   = (const float*)d_in[4];
  const float* WL   = (const float*)d_in[5];
  const float* rsc  = (const float*)d_in[6];
  const float* Wp   = (const float*)d_in[7];
  const float* bp   = (const float*)d_in[8];
  float* out = (float*)d_out;

  float* xxws = (float*)d_ws;                                    // 4*4096 f32
  unsigned short* Mt = (unsigned short*)((char*)d_ws + 4 * 4096 * sizeof(float));

  hipMemsetAsync(d_ws, 0, (size_t)4 * 4096 * sizeof(float), stream);
  hipLaunchKernelGGL(k1_xx, dim3(32, 4), dim3(256), 0, stream, x, xxws);
  hipLaunchKernelGGL(k2_attn, dim3(16), dim3(256), 0, stream, xxws, Wq, Wk, rsc, Wp, Mt);
  hipLaunchKernelGGL(k3_out, dim3(128, 4), dim3(256), 0, stream, x, illu, Wv, WL, Mt, bp, out);
}